// Round 4
// baseline (317.894 us; speedup 1.0000x reference)
//
#include <hip/hip_runtime.h>

// LinearRNN as truncated FIR convolution:
//   y_t = sum_{i=0}^{32} G_i u_{t-i} + C A^t x0,   G_0 = D, G_i = C A^{i-1} B.
// R4: k_conv occupancy 2->3 blocks/CU (ROWS 256, 41.5 KB LDS) — R3 showed all
// pipes <26% busy at 2 waves/SIMD = latency-bound. k_prep: z-shuffle chains
// moved off the sequential M-chain into a parallel tail (M_i staged in ws).

#define T_LEN  262144
#define NTAP   33      // taps 0..32
#define ZLEN   48      // x0-correction horizon
#define ROWS   256     // output rows per conv block
#define WROWS  64      // rows per wave
#define HALO   32

typedef __attribute__((ext_vector_type(8))) short  short8;
typedef __attribute__((ext_vector_type(4))) float  floatx4;

static __device__ __forceinline__ unsigned short f2bf(float f) {
    unsigned int x = __float_as_uint(f);
    x += 0x7fffu + ((x >> 16) & 1u);     // RNE (finite normals)
    return (unsigned short)(x >> 16);
}
static __device__ __forceinline__ float bf2f(unsigned short u) {
    return __uint_as_float(((unsigned int)u) << 16);
}

// ---------------------------------------------------------------------------
// K1: G (bf16, [tap][p][m]) + M_i = C A^i (bf16, ws) + tail phase Z = M x0.
// One block, 4 waves; wave w owns rows 16w..16w+15 of the M chain (no
// barriers in the chain: row-slices evolve independently, in-order LDS).
// ---------------------------------------------------------------------------
__global__ __launch_bounds__(256, 1) void k_prep(
    const float* __restrict__ A, const float* __restrict__ B,
    const float* __restrict__ C, const float* __restrict__ D,
    const float* __restrict__ x0, unsigned short* __restrict__ gG,
    float* __restrict__ gZ, unsigned short* __restrict__ gM)
{
    __shared__ unsigned short At[64][72];  // At[j][k] = A[k][j]
    __shared__ unsigned short Bt[64][72];  // Bt[m][n] = B[n][m]
    __shared__ unsigned short M0[64][72];
    __shared__ unsigned short M1[64][72];
    __shared__ float x0s[64];
    const int tid = threadIdx.x;
    const int wv = tid >> 6, lane = tid & 63, l15 = lane & 15, q = lane >> 4;

#pragma unroll
    for (int e = 0; e < 16; ++e) {
        int f = e * 256 + tid;
        int r = f >> 6, cc = f & 63;
        At[cc][r] = f2bf(A[f]);            // transpose
        Bt[cc][r] = f2bf(B[f]);            // transpose
        unsigned short cb = f2bf(C[f]);
        M0[r][cc] = cb;                    // M_0 = C
        gM[f]     = cb;                    // stash M_0 for the z tail
        gG[f]     = f2bf(D[f]);            // G_0 = D
    }
    if (tid < 64) x0s[tid] = x0[tid];
    __syncthreads();

    // loop-invariant b-frags (MFMA operands stay resident)
    short8 bA[2][4], bB[2][4];
#pragma unroll
    for (int kb = 0; kb < 2; ++kb)
#pragma unroll
        for (int nt = 0; nt < 4; ++nt) {
            bA[kb][nt] = *(const short8*)&At[l15 + 16*nt][kb*32 + q*8];
            bB[kb][nt] = *(const short8*)&Bt[l15 + 16*nt][kb*32 + q*8];
        }

    unsigned short (*Ms)[72] = M0;
    unsigned short (*Md)[72] = M1;
    for (int i = 1; i < ZLEN; ++i) {
        short8 a0 = *(const short8*)&Ms[16*wv + l15][q*8];
        short8 a1 = *(const short8*)&Ms[16*wv + l15][32 + q*8];

        // ---- M_i = M_{i-1} @ A  (the only thing on the critical path)
        floatx4 m[4];
#pragma unroll
        for (int nt = 0; nt < 4; ++nt) {
            m[nt] = (floatx4){0.f, 0.f, 0.f, 0.f};
            m[nt] = __builtin_amdgcn_mfma_f32_16x16x32_bf16(a0, bA[0][nt], m[nt], 0, 0, 0);
            m[nt] = __builtin_amdgcn_mfma_f32_16x16x32_bf16(a1, bA[1][nt], m[nt], 0, 0, 0);
        }
#pragma unroll
        for (int nt = 0; nt < 4; ++nt)
#pragma unroll
            for (int r = 0; r < 4; ++r) {
                unsigned short mb = f2bf(m[nt][r]);
                int row = 16*wv + q*4 + r, col = l15 + 16*nt;
                Md[row][col] = mb;                          // chain
                gM[(size_t)i*4096 + row*64 + col] = mb;     // for z tail
            }

        // ---- G_i = M_{i-1} @ B  (off the path)
        if (i < NTAP) {
            floatx4 g[4];
#pragma unroll
            for (int nt = 0; nt < 4; ++nt) {
                g[nt] = (floatx4){0.f, 0.f, 0.f, 0.f};
                g[nt] = __builtin_amdgcn_mfma_f32_16x16x32_bf16(a0, bB[0][nt], g[nt], 0, 0, 0);
                g[nt] = __builtin_amdgcn_mfma_f32_16x16x32_bf16(a1, bB[1][nt], g[nt], 0, 0, 0);
            }
#pragma unroll
            for (int nt = 0; nt < 4; ++nt)
#pragma unroll
                for (int r = 0; r < 4; ++r)
                    gG[(size_t)i*4096 + (16*wv + q*4 + r)*64 + l15 + 16*nt] = f2bf(g[nt][r]);
        }

        unsigned short (*tmp)[72] = Ms; Ms = Md; Md = tmp;
    }
    __syncthreads();   // drains vmem; single block, same CU -> gM visible

    // ---- tail: z[i][p] = sum_m M_i[p][m] * x0[m], parallel over 256 threads
    for (int k = tid; k < ZLEN * 64; k += 256) {
        const unsigned short* Mp = gM + (size_t)(k >> 6) * 4096 + (k & 63) * 64;
        float v = 0.f;
#pragma unroll
        for (int mm = 0; mm < 64; ++mm) v = fmaf(bf2f(Mp[mm]), x0s[mm], v);
        gZ[k] = v;
    }
}

// ---------------------------------------------------------------------------
// K2: the convolution. 256 thr (4 waves), 256 output rows + 32 halo in LDS
// (41.5 KB -> 3 blocks/CU). Wave w owns rows [64w, 64w+64): 4 mt x 4 nt
// tiles, 33 taps x 2 k-steps. G double-buffered from L1/L2.
// ---------------------------------------------------------------------------
__device__ __forceinline__ void loadG(short8 (&b)[8],
                                      const unsigned short* __restrict__ gG,
                                      int i, int l15, int q)
{
#pragma unroll
    for (int kb = 0; kb < 2; ++kb)
#pragma unroll
        for (int nt = 0; nt < 4; ++nt)
            b[kb*4 + nt] = *(const short8*)(gG + (size_t)i*4096
                              + (l15 + 16*nt)*64 + kb*32 + q*8);
}

__device__ __forceinline__ void tapStep(floatx4 (&acc)[4][4],
                                        const unsigned short (*uS)[72],
                                        const short8 (&b)[8],
                                        int i, int wv, int l15, int q)
{
    const int rbase = wv*WROWS + l15 + HALO - i;
#pragma unroll
    for (int kb = 0; kb < 2; ++kb)
#pragma unroll
        for (int mt = 0; mt < 4; ++mt) {
            short8 a = *(const short8*)&uS[rbase + mt*16][kb*32 + q*8];
#pragma unroll
            for (int nt = 0; nt < 4; ++nt)
                acc[mt][nt] = __builtin_amdgcn_mfma_f32_16x16x32_bf16(
                    a, b[kb*4 + nt], acc[mt][nt], 0, 0, 0);
        }
}

__global__ __launch_bounds__(256, 3) void k_conv(
    const float* __restrict__ u, const unsigned short* __restrict__ gG,
    const float* __restrict__ gZ, float* __restrict__ out)
{
    __shared__ __align__(16) unsigned short uS[ROWS + HALO][72];   // 41,472 B
    const int tid = threadIdx.x;
    const int wv = tid >> 6, lane = tid & 63, l15 = lane & 15, q = lane >> 4;
    const int t0 = blockIdx.x * ROWS;

    // stage u rows [t0-32, t0+256) as bf16 (rows < 0 -> zeros, block 0 only)
    {
        const float4* u4 = (const float4*)u;
        const int base4 = (t0 - HALO) * 16;
#pragma unroll
        for (int e = 0; e < 18; ++e) {
            int f = e * 256 + tid;              // 4608 float4 total
            float4 v = make_float4(0.f, 0.f, 0.f, 0.f);
            if (base4 + f >= 0) v = u4[base4 + f];
            int r = f >> 4, cx = (f & 15) * 4;
            uS[r][cx+0] = f2bf(v.x); uS[r][cx+1] = f2bf(v.y);
            uS[r][cx+2] = f2bf(v.z); uS[r][cx+3] = f2bf(v.w);
        }
    }
    __syncthreads();

    floatx4 acc[4][4];
#pragma unroll
    for (int mt = 0; mt < 4; ++mt)
#pragma unroll
        for (int nt = 0; nt < 4; ++nt) acc[mt][nt] = (floatx4){0.f, 0.f, 0.f, 0.f};

    short8 b0[8], b1[8];
    loadG(b0, gG, 0, l15, q);
    for (int ii = 0; ii < 16; ++ii) {           // taps 2ii, 2ii+1
        loadG(b1, gG, 2*ii + 1, l15, q);
        tapStep(acc, uS, b0, 2*ii, wv, l15, q);
        loadG(b0, gG, 2*ii + 2, l15, q);        // tap 32 prefetched at ii=15
        tapStep(acc, uS, b1, 2*ii + 1, wv, l15, q);
    }
    tapStep(acc, uS, b0, 32, wv, l15, q);

    // epilogue: C/D layout row = q*4+r (+16mt +64wv), col = l15 (+16nt)
    const bool zblk = (blockIdx.x == 0 && wv == 0);
#pragma unroll
    for (int mt = 0; mt < 4; ++mt)
#pragma unroll
        for (int nt = 0; nt < 4; ++nt) {
            const int p = l15 + 16*nt;
#pragma unroll
            for (int r = 0; r < 4; ++r) {
                int tl = wv*WROWS + mt*16 + q*4 + r;
                float v = acc[mt][nt][r];
                if (zblk && mt < 3) v += gZ[(mt*16 + q*4 + r)*64 + p];  // t < 48
                out[(size_t)(t0 + tl)*64 + p] = v;
            }
        }
}

extern "C" void kernel_launch(void* const* d_in, const int* in_sizes, int n_in,
                              void* d_out, int out_size, void* d_ws, size_t ws_size,
                              hipStream_t stream) {
    const float* u  = (const float*)d_in[0];
    const float* x0 = (const float*)d_in[1];
    const float* A  = (const float*)d_in[2];
    const float* B  = (const float*)d_in[3];
    const float* C  = (const float*)d_in[4];
    const float* D  = (const float*)d_in[5];
    float* out = (float*)d_out;

    unsigned short* gG = (unsigned short*)d_ws;                  // 33*4096 bf16
    float*          gZ = (float*)((char*)d_ws + 272384);         // 48*64 fp32
    unsigned short* gM = (unsigned short*)((char*)d_ws + 286720);// 48*4096 bf16

    hipLaunchKernelGGL(k_prep, dim3(1), dim3(256), 0, stream,
                       A, B, C, D, x0, gG, gZ, gM);
    hipLaunchKernelGGL(k_conv, dim3(T_LEN / ROWS), dim3(256), 0, stream,
                       u, gG, gZ, out);
}